// Round 1
// baseline (880.024 us; speedup 1.0000x reference)
//
#include <hip/hip_runtime.h>
#include <float.h>
#include <math.h>

#define DIM 512
#define VDIM 512
#define ROWS_PER_WAVE 32
#define WAVES_PER_BLOCK 4

// Kernel A: one wave per row-chunk. Each wave computes dot(keys[row], query)
// for ROWS_PER_WAVE consecutive rows (lane holds 8 floats of the row; full
// 64-lane shfl_xor butterfly reduce), maintains online-softmax state
// (running max m, running sum s = sum exp(logit - m), argmax index), then the
// 4 waves of the block combine via LDS and write one partial per block.
__global__ __launch_bounds__(256) void logits_partials(
    const float* __restrict__ query,
    const float* __restrict__ keys,
    int n,
    float* __restrict__ pmax,
    float* __restrict__ psum,
    int*   __restrict__ pidx)
{
    const int lane = threadIdx.x & 63;
    const int wave = threadIdx.x >> 6;

    // Query fragment: 8 floats per lane (64*8 = 512 = DIM). L1-cached.
    const float4 q0 = *(const float4*)(query + lane * 8);
    const float4 q1 = *(const float4*)(query + lane * 8 + 4);

    const int waveId = blockIdx.x * WAVES_PER_BLOCK + wave;
    const int row0   = waveId * ROWS_PER_WAVE;

    float m  = -FLT_MAX;
    float s  = 0.0f;
    int   mi = -1;

    for (int r = 0; r < ROWS_PER_WAVE; ++r) {
        const int row = row0 + r;
        if (row >= n) break;
        const float* kp = keys + (size_t)row * DIM + lane * 8;
        const float4 k0 = *(const float4*)kp;
        const float4 k1 = *(const float4*)(kp + 4);
        float d = k0.x*q0.x + k0.y*q0.y + k0.z*q0.z + k0.w*q0.w
                + k1.x*q1.x + k1.y*q1.y + k1.z*q1.z + k1.w*q1.w;
        // 64-lane butterfly: all lanes end with the full dot product.
        #pragma unroll
        for (int off = 32; off > 0; off >>= 1)
            d += __shfl_xor(d, off, 64);
        // Online softmax update (uniform across the wave).
        if (d > m) {
            s = s * expf(m - d) + 1.0f;   // expf(-huge)=0 on first iter
            m = d;
            mi = row;
        } else {
            s += expf(d - m);             // underflows to 0 for distant rows
        }
    }

    // Combine the block's 4 waves.
    __shared__ float sm[WAVES_PER_BLOCK];
    __shared__ float ss[WAVES_PER_BLOCK];
    __shared__ int   si[WAVES_PER_BLOCK];
    if (lane == 0) { sm[wave] = m; ss[wave] = s; si[wave] = mi; }
    __syncthreads();
    if (threadIdx.x == 0) {
        float M = sm[0]; int I = si[0];
        #pragma unroll
        for (int w = 1; w < WAVES_PER_BLOCK; ++w)
            if (sm[w] > M) { M = sm[w]; I = si[w]; }
        float S = 0.0f;
        #pragma unroll
        for (int w = 0; w < WAVES_PER_BLOCK; ++w)
            S += ss[w] * expf(sm[w] - M);
        pmax[blockIdx.x] = M;
        psum[blockIdx.x] = S;
        pidx[blockIdx.x] = I;
    }
}

// Kernel B: single block. Reduce the per-block partials to the global max /
// argmax / softmax denominator, then emit out = values[argmax] / denom.
__global__ __launch_bounds__(512) void finalize(
    const float* __restrict__ pmax,
    const float* __restrict__ psum,
    const int*   __restrict__ pidx,
    int nb,
    const float* __restrict__ values,
    float* __restrict__ out)
{
    __shared__ float sm[512];
    __shared__ int   si[512];
    __shared__ float ssum[512];

    const int tid = threadIdx.x;

    // Pass 1: global max + argmax.
    float m = -FLT_MAX; int mi = -1;
    for (int b = tid; b < nb; b += 512) {
        const float mb = pmax[b];
        if (mb > m) { m = mb; mi = pidx[b]; }
    }
    sm[tid] = m; si[tid] = mi;
    __syncthreads();
    #pragma unroll
    for (int off = 256; off > 0; off >>= 1) {
        if (tid < off) {
            if (sm[tid + off] > sm[tid]) { sm[tid] = sm[tid + off]; si[tid] = si[tid + off]; }
        }
        __syncthreads();
    }
    const float M = sm[0];
    const int   I = si[0];

    // Pass 2: denominator = sum_b s_b * exp(m_b - M).
    float s = 0.0f;
    for (int b = tid; b < nb; b += 512)
        s += psum[b] * expf(pmax[b] - M);
    ssum[tid] = s;
    __syncthreads();
    #pragma unroll
    for (int off = 256; off > 0; off >>= 1) {
        if (tid < off) ssum[tid] += ssum[tid + off];
        __syncthreads();
    }
    const float inv = 1.0f / ssum[0];

    // Output: values[argmax] scaled by 1/denom.
    for (int v = tid; v < VDIM; v += 512)
        out[v] = values[(size_t)I * VDIM + v] * inv;
}

extern "C" void kernel_launch(void* const* d_in, const int* in_sizes, int n_in,
                              void* d_out, int out_size, void* d_ws, size_t ws_size,
                              hipStream_t stream) {
    const float* query  = (const float*)d_in[0];
    const float* keys   = (const float*)d_in[1];
    const float* values = (const float*)d_in[2];
    float* out = (float*)d_out;

    const int n = in_sizes[1] / DIM;  // 262144

    const int rowsPerBlock = ROWS_PER_WAVE * WAVES_PER_BLOCK;  // 128
    const int nb = (n + rowsPerBlock - 1) / rowsPerBlock;      // 2048

    float* pmax = (float*)d_ws;
    float* psum = pmax + nb;
    int*   pidx = (int*)(psum + nb);

    logits_partials<<<nb, 256, 0, stream>>>(query, keys, n, pmax, psum, pidx);
    finalize<<<1, 512, 0, stream>>>(pmax, psum, pidx, nb, values, out);
}